// Round 10
// baseline (274.540 us; speedup 1.0000x reference)
//
#include <hip/hip_runtime.h>

typedef __bf16 bf16_t;
typedef __bf16 bf16x2 __attribute__((ext_vector_type(2)));
typedef __bf16 bf16x8 __attribute__((ext_vector_type(8)));
typedef float f32x4 __attribute__((ext_vector_type(4)));
typedef float f32x16 __attribute__((ext_vector_type(16)));
typedef unsigned u32;
typedef unsigned u32x4 __attribute__((ext_vector_type(4)));

#define N_PIX 4096
#define CFEAT 256
#define CKEY 32
#define NBATCH 4
#define LOG2E 1.4426950408889634f

static __device__ __forceinline__ f32x4 mfma16(bf16x8 a, bf16x8 b, f32x4 c) {
    return __builtin_amdgcn_mfma_f32_16x16x32_bf16(a, b, c, 0, 0, 0);
}
static __device__ __forceinline__ f32x16 mfma32(bf16x8 a, bf16x8 b, f32x16 c) {
    return __builtin_amdgcn_mfma_f32_32x32x16_bf16(a, b, c, 0, 0, 0);
}
static __device__ __forceinline__ void glds16(const void* g, void* l) {
    __builtin_amdgcn_global_load_lds(
        (const __attribute__((address_space(1))) void*)g,
        (__attribute__((address_space(3))) void*)l, 16, 0, 0);
}
static __device__ __forceinline__ float fexp2(float x) {
#if __has_builtin(__builtin_amdgcn_exp2f)
    return __builtin_amdgcn_exp2f(x);
#else
    return exp2f(x);
#endif
}
static __device__ __forceinline__ u32 pack2(float a, float b) {
    bf16x2 t; t[0] = (bf16_t)a; t[1] = (bf16_t)b;
    return __builtin_bit_cast(u32, t);
}
// mfma32 D-layout -> B-operand layout lane-half exchange (validated r9)
static __device__ __forceinline__ void halfswap(u32& a, u32& b) {
#if __has_builtin(__builtin_amdgcn_permlane32_swap)
    auto r = __builtin_amdgcn_permlane32_swap(a, b, false, false);
    a = r[0]; b = r[1];
#else
    const bool hi = ((threadIdx.x & 63) >= 32);
    u32 xa = (u32)__shfl_xor((int)a, 32);
    u32 xb = (u32)__shfl_xor((int)b, 32);
    a = hi ? xb : a;
    b = hi ? b : xa;
#endif
}

// ---------------------------------------------------------------------------
// projqk (r9 verbatim): Yt[b][n][32] = bf16(scale*(W.X + bias)), Q pre-scaled
// by log2e. grid (N/64, 2, B), block 256. LDS repack -> coalesced 16B stores.
// ---------------------------------------------------------------------------
__global__ __launch_bounds__(256) void projqk_kernel(
    const float* __restrict__ Wq, const float* __restrict__ bq, const float* __restrict__ Xq,
    const float* __restrict__ Wk, const float* __restrict__ bk, const float* __restrict__ Xk,
    bf16_t* __restrict__ Qt, bf16_t* __restrict__ Kt)
{
    __shared__ __attribute__((aligned(16))) bf16_t T[64][40];
    const int lane = threadIdx.x & 63, wave = threadIdx.x >> 6;
    const int g = lane >> 4, ln = lane & 15;
    const bool isK = (blockIdx.y == 1);
    const float* W    = isK ? Wk : Wq;
    const float* bias = isK ? bk : bq;
    const float scale = isK ? 1.0f : LOG2E;
    const float* X  = (isK ? Xk : Xq) + (size_t)blockIdx.z * CFEAT * N_PIX;
    bf16_t*      Yt = (isK ? Kt : Qt) + (size_t)blockIdx.z * N_PIX * CKEY;

    const int m_base = (wave & 1) * 16;
    const int n_loc  = (wave >> 1) * 32;
    const int n_base = blockIdx.x * 64 + n_loc;

    f32x4 zero = {0.f, 0.f, 0.f, 0.f};
    f32x4 acc[2] = {zero, zero};
    for (int k0 = 0; k0 < CFEAT; k0 += 32) {
        bf16x8 a;
        const float* wp = W + (size_t)(m_base + ln) * CFEAT + k0 + g * 8;
#pragma unroll
        for (int j = 0; j < 8; ++j) a[j] = (bf16_t)wp[j];
#pragma unroll
        for (int nt = 0; nt < 2; ++nt) {
            const float* xp = X + (size_t)(k0 + g * 8) * N_PIX + n_base + nt * 16 + ln;
            bf16x8 bfr;
#pragma unroll
            for (int j = 0; j < 8; ++j) bfr[j] = (bf16_t)xp[(size_t)j * N_PIX];
            acc[nt] = mfma16(a, bfr, acc[nt]);
        }
    }
#pragma unroll
    for (int nt = 0; nt < 2; ++nt)
#pragma unroll
        for (int r = 0; r < 4; ++r) {
            const int ck = m_base + g * 4 + r;
            T[n_loc + nt * 16 + ln][ck] = (bf16_t)((acc[nt][r] + bias[ck]) * scale);
        }
    __syncthreads();
    const int n  = threadIdx.x >> 2;
    const int sg = threadIdx.x & 3;
    bf16x8 row = *(const bf16x8*)&T[n][sg * 8];
    *(bf16x8*)&Yt[(size_t)(blockIdx.x * 64 + n) * CKEY + sg * 8] = row;
}

// ---------------------------------------------------------------------------
// projv (r9 verbatim): V[b][c][n] = bf16(Wv.X + bv). grid (N/32, 2, B).
// ---------------------------------------------------------------------------
__global__ __launch_bounds__(256, 4) void projv_kernel(
    const float* __restrict__ W, const float* __restrict__ bias,
    const float* __restrict__ X, bf16_t* __restrict__ V)
{
    const int lane = threadIdx.x & 63, wave = threadIdx.x >> 6;
    const int g = lane >> 4, ln = lane & 15;
    const int b = blockIdx.z;
    const int n_base = blockIdx.x * 32;
    const int c_wave = blockIdx.y * 128 + wave * 32;
    const float* Xb = X + (size_t)b * CFEAT * N_PIX;
    bf16_t*      Vb = V + (size_t)b * CFEAT * N_PIX;

    f32x4 zero = {0.f, 0.f, 0.f, 0.f};
    f32x4 acc[2][2];
#pragma unroll
    for (int mt = 0; mt < 2; ++mt) { acc[mt][0] = zero; acc[mt][1] = zero; }

    for (int k0 = 0; k0 < CFEAT; k0 += 32) {
        bf16x8 bfr[2];
#pragma unroll
        for (int nt = 0; nt < 2; ++nt) {
            const float* xp = Xb + (size_t)(k0 + g * 8) * N_PIX + n_base + nt * 16 + ln;
#pragma unroll
            for (int j = 0; j < 8; ++j) bfr[nt][j] = (bf16_t)xp[(size_t)j * N_PIX];
        }
#pragma unroll
        for (int mt = 0; mt < 2; ++mt) {
            const float* wp = W + (size_t)(c_wave + mt * 16 + ln) * CFEAT + k0 + g * 8;
            bf16x8 a;
#pragma unroll
            for (int j = 0; j < 8; ++j) a[j] = (bf16_t)wp[j];
            acc[mt][0] = mfma16(a, bfr[0], acc[mt][0]);
            acc[mt][1] = mfma16(a, bfr[1], acc[mt][1]);
        }
    }
#pragma unroll
    for (int mt = 0; mt < 2; ++mt)
#pragma unroll
        for (int nt = 0; nt < 2; ++nt)
#pragma unroll
            for (int r = 0; r < 4; ++r) {
                const int m = c_wave + mt * 16 + g * 4 + r;
                const int n = n_base + nt * 16 + ln;
                Vb[(size_t)m * N_PIX + n] = (bf16_t)(acc[mt][nt][r] + bias[m]);
            }
}

// ---------------------------------------------------------------------------
// pv: out = gamma * softmax(QK^T).V / l + feat (max-free, exp2; Q pre-scaled).
// BARRIER-FREE wave-self-paced streaming:
//   wave tile = 32i x 64c x 2048j (j-split 2), j-tile 32 -> 64 iters.
//   K and V staged via glds16 into WAVE-PRIVATE LDS (V dbuf 2x4KB, K 2KB);
//   one manual s_waitcnt vmcnt(0) per iter, NO __syncthreads in the loop.
//   Register-held P via permlane halfswap (r9, conflicts=0).
//   Block = 128 thr = the 2 j-half waves of one (i,c) tile; ONE barrier at
//   the end to combine (O, l) via LDS. grid (4 c-splits, 128 i-tiles, B)
//   = 2048 blocks -> 8 blocks/CU, 16 waves/CU. LDS 20480 B/block.
// ---------------------------------------------------------------------------
__global__ __launch_bounds__(128, 4) void pv_kernel(
    const bf16_t* __restrict__ Qt, const bf16_t* __restrict__ Kt,
    const bf16_t* __restrict__ V,
    const float* __restrict__ features, const float* __restrict__ gamma,
    float* __restrict__ out)
{
    // [wave][buf][64c*32j chunk-major jc*64+c], [wave][32ck x 32j chunk-major]
    __shared__ __attribute__((aligned(16))) bf16_t Vlds[2][2][2048]; // 16 KB
    __shared__ __attribute__((aligned(16))) bf16_t Klds[2][1024];    //  4 KB

    const int lane = threadIdx.x & 63, wave = threadIdx.x >> 6;  // wave = jh
    const int l31 = lane & 31, h = lane >> 5;
    const int b = blockIdx.z;
    const int i0 = blockIdx.y * 32;
    const int c_blk = blockIdx.x * 64;
    const int jbase = wave * 2048;                 // this wave's j-half

    const bf16_t* Qb = Qt + (size_t)b * N_PIX * CKEY;
    const bf16_t* Kb = Kt + (size_t)b * N_PIX * CKEY;
    const bf16_t* Vb = V + (size_t)b * CFEAT * N_PIX;
    bf16_t* Kw = &Klds[wave][0];

    // Q B-frags (hoisted): B[k=16s+8h+t][n=i=l31]
    bf16x8 qf[2];
#pragma unroll
    for (int s = 0; s < 2; ++s)
        qf[s] = *(const bf16x8*)&Qb[(size_t)(i0 + l31) * CKEY + s * 16 + h * 8];

    // staging source bases
    const bf16_t* vsrc = Vb + (size_t)(c_blk + lane) * N_PIX;        // + j0 + q*8
    const int koff = (lane & 31) * CKEY + (lane >> 5) * 8;           // + j0*32 + q*16

    f32x16 acc[2];
#pragma unroll
    for (int ct = 0; ct < 2; ++ct)
#pragma unroll
        for (int r = 0; r < 16; ++r) acc[ct][r] = 0.f;
    float lsum = 0.f;

    // ---- prologue: stage K(0), V(0) ----
#pragma unroll
    for (int q = 0; q < 2; ++q) glds16(Kb + (size_t)jbase * CKEY + koff + q * 16, &Kw[q * 512]);
#pragma unroll
    for (int q = 0; q < 4; ++q) glds16(vsrc + jbase + q * 8, &Vlds[wave][0][q * 512]);

    for (int n = 0; n < 64; ++n) {
        const int j0 = jbase + n * 32;
        // ---- wait: K(n) + V(n) DMA landed (wave-level; no barrier) ----
        asm volatile("s_waitcnt vmcnt(0)" ::: "memory");

        // ---- V(n+1) prefetch into other buffer (wrap on last iter) ----
        const int jn = jbase + ((n + 1) & 63) * 32;
        const int bn = (n + 1) & 1;
#pragma unroll
        for (int q = 0; q < 4; ++q) glds16(vsrc + jn + q * 8, &Vlds[wave][bn][q * 512]);

        // ---- S^T(n): A = K rows from LDS (chunk-major, conflict-free) ----
        const bf16x8 kf0 = *(const bf16x8*)&Kw[((h)     * 32 + l31) * 8];  // ck 8h+t
        const bf16x8 kf1 = *(const bf16x8*)&Kw[((2 + h) * 32 + l31) * 8];  // ck 16+8h+t
        f32x16 z;
#pragma unroll
        for (int r = 0; r < 16; ++r) z[r] = 0.f;
        f32x16 st = mfma32(kf1, qf[1], mfma32(kf0, qf[0], z));

        // ---- K(n+1) prefetch (single buffer: safe, K(n) reads retired) ----
#pragma unroll
        for (int q = 0; q < 2; ++q) glds16(Kb + (size_t)jn * CKEY + koff + q * 16, &Kw[q * 512]);

        // ---- exp2 + pack + halfswap -> PV B-frags (register P) ----
        float e[16];
#pragma unroll
        for (int r = 0; r < 16; ++r) { e[r] = fexp2(st[r]); lsum += e[r]; }
        u32 p0a = pack2(e[0], e[1]),   p0b = pack2(e[2], e[3]);
        u32 p1a = pack2(e[4], e[5]),   p1b = pack2(e[6], e[7]);
        u32 p2a = pack2(e[8], e[9]),   p2b = pack2(e[10], e[11]);
        u32 p3a = pack2(e[12], e[13]), p3b = pack2(e[14], e[15]);
        halfswap(p0a, p1a); halfswap(p0b, p1b);
        halfswap(p2a, p3a); halfswap(p2b, p3b);
        bf16x8 pb[2];
        pb[0] = __builtin_bit_cast(bf16x8, (u32x4){p0a, p0b, p1a, p1b});  // j 0..15
        pb[1] = __builtin_bit_cast(bf16x8, (u32x4){p2a, p2b, p3a, p3b});  // j 16..31

        // ---- PV(n): A = V chunks (jc = 2ks+h, c = ct*32+l31) ----
        const bf16_t* Vt = &Vlds[wave][n & 1][0];
#pragma unroll
        for (int ks = 0; ks < 2; ++ks)
#pragma unroll
            for (int ct = 0; ct < 2; ++ct) {
                const bf16x8 va = *(const bf16x8*)&Vt[((2 * ks + h) * 64 + ct * 32 + l31) * 8];
                acc[ct] = mfma32(va, pb[ks], acc[ct]);
            }
    }

    // drain trailing prefetch DMA before reusing LDS for the reduction
    asm volatile("s_waitcnt vmcnt(0)" ::: "memory");

    // wave-total l_i (both h-quarters of this j-half)
    lsum += __shfl_xor(lsum, 32);

    // ---- combine the two j-half waves (single barrier) ----
    float* red  = (float*)&Vlds[1][0][0];   // 2048 floats = wave1's V buffers
    float* lred = (float*)&Klds[1][0];
    if (wave == 1) {
#pragma unroll
        for (int ct = 0; ct < 2; ++ct)
#pragma unroll
            for (int r = 0; r < 16; ++r) red[(ct * 16 + r) * 64 + lane] = acc[ct][r];
        if (h == 0) lred[l31] = lsum;
    }
    __syncthreads();
    if (wave == 0) {
        const float s_lane = gamma[0] / (lsum + lred[l31]);
#pragma unroll
        for (int ct = 0; ct < 2; ++ct)
#pragma unroll
            for (int r = 0; r < 16; ++r) {
                const float o = acc[ct][r] + red[(ct * 16 + r) * 64 + lane];
                const int row = (r & 3) + 8 * (r >> 2) + 4 * h;   // mfma32 D row
                const int c = c_blk + ct * 32 + row;
                const int i = i0 + l31;
                const size_t idx = ((size_t)b * CFEAT + c) * N_PIX + i;
                out[idx] = s_lane * o + features[idx];
            }
    }
}

// ---------------------------------------------------------------------------
extern "C" void kernel_launch(void* const* d_in, const int* in_sizes, int n_in,
                              void* d_out, int out_size, void* d_ws, size_t ws_size,
                              hipStream_t stream) {
    const float* features   = (const float*)d_in[0];
    const float* conditions = (const float*)d_in[1];
    const float* Wq  = (const float*)d_in[2];
    const float* bq  = (const float*)d_in[3];
    const float* Wk  = (const float*)d_in[4];
    const float* bk  = (const float*)d_in[5];
    const float* Wv  = (const float*)d_in[6];
    const float* bv  = (const float*)d_in[7];
    const float* gam = (const float*)d_in[8];
    float* out = (float*)d_out;

    // ws (bf16): Qt 1MB | Kt 1MB | V 8MB
    bf16_t* Qt = (bf16_t*)d_ws;
    bf16_t* Kt = Qt + (size_t)NBATCH * N_PIX * CKEY;
    bf16_t* Vw = Kt + (size_t)NBATCH * N_PIX * CKEY;

    projqk_kernel<<<dim3(N_PIX / 64, 2, NBATCH), 256, 0, stream>>>(
        Wq, bq, conditions, Wk, bk, features, Qt, Kt);
    projv_kernel<<<dim3(N_PIX / 32, 2, NBATCH), 256, 0, stream>>>(Wv, bv, features, Vw);
    pv_kernel<<<dim3(CFEAT / 64, N_PIX / 32, NBATCH), 128, 0, stream>>>(
        Qt, Kt, Vw, features, gam, out);
}